// Round 1
// baseline (119.683 us; speedup 1.0000x reference)
//
#include <hip/hip_runtime.h>

#define STU  20000
#define ITEM 8000
#define CONC 128
#define EMB  32
#define BATCH 128

__device__ __forceinline__ float sigmoidf(float x) { return 1.f / (1.f + __expf(-x)); }

// ---------------- Kernel 1: stu_conc[b][c] = sigmoid(stu_emb[idx[b]] . w1[c] + b1[c]); gs[b] = gw_stu[idx[b]]
__global__ __launch_bounds__(256) void stu_kernel(
    const int* __restrict__ stu_list, const float* __restrict__ stu_emb,
    const float* __restrict__ w1, const float* __restrict__ b1,
    const float* __restrict__ gw_stu,
    float* __restrict__ sc_out,   // [BATCH][CONC]
    float* __restrict__ gs_out)   // [BATCH]
{
    int tid = blockIdx.x * 256 + threadIdx.x;   // grid 64 -> 16384 threads
    int b = tid >> 7, c = tid & 127;
    int sid = stu_list[b] - 1;
    float d = b1[c];
    const float4* wrow = (const float4*)(w1 + c * EMB);
    const float4* erow = (const float4*)(stu_emb + (size_t)sid * EMB);
#pragma unroll
    for (int e4 = 0; e4 < EMB / 4; ++e4) {
        float4 w = wrow[e4], em = erow[e4];
        d += w.x * em.x + w.y * em.y + w.z * em.z + w.w * em.w;
    }
    sc_out[tid] = sigmoidf(d);
    if (c == 0) gs_out[b] = gw_stu[sid];
}

// ---------------- Kernel 2: per item i: t[i] = sum_c Q[i,c]*wp[c]*item_conc[i,c];  qa[i] = sum_c Q[i,c]*gw_Q[c]
// One wave (64 lanes) per item; each lane handles 2 concepts.
__global__ __launch_bounds__(256) void item_kernel(
    const float* __restrict__ item_emb, const float* __restrict__ Q,
    const float* __restrict__ w1, const float* __restrict__ b1,
    const float* __restrict__ wp, const float* __restrict__ gw_Q,
    float* __restrict__ t_out,    // [ITEM]
    float* __restrict__ qa_out)   // [ITEM]
{
    int wave = (blockIdx.x * blockDim.x + threadIdx.x) >> 6;
    int lane = threadIdx.x & 63;
    if (wave >= ITEM) return;
    const int i = wave;

    const float4* erow = (const float4*)(item_emb + (size_t)i * EMB);
    float4 e[EMB / 4];
#pragma unroll
    for (int e4 = 0; e4 < EMB / 4; ++e4) e[e4] = erow[e4];

    float acc_t = 0.f, acc_qa = 0.f;
#pragma unroll
    for (int cc = 0; cc < 2; ++cc) {
        int c = lane + cc * 64;
        float d = b1[c];
        const float4* wrow = (const float4*)(w1 + c * EMB);
#pragma unroll
        for (int e4 = 0; e4 < EMB / 4; ++e4) {
            float4 w = wrow[e4];
            d += w.x * e[e4].x + w.y * e[e4].y + w.z * e[e4].z + w.w * e[e4].w;
        }
        float ic = sigmoidf(d);
        float q = Q[(size_t)i * CONC + c];
        acc_t  += q * wp[c] * ic;
        acc_qa += q * gw_Q[c];
    }
#pragma unroll
    for (int off = 32; off; off >>= 1) {
        acc_t  += __shfl_down(acc_t, off);
        acc_qa += __shfl_down(acc_qa, off);
    }
    if (lane == 0) { t_out[i] = acc_t; qa_out[i] = acc_qa; }
}

// ---------------- Kernel 3: out[b][i] = g2 + (1-g2)*P
// Tile: 16 b x 64 i per block of 256 threads; each thread: 4 b x 1 i.
__global__ __launch_bounds__(256) void out_kernel(
    const float* __restrict__ Q, const float* __restrict__ wp,
    const float* __restrict__ disc, const float* __restrict__ t_arr,
    const float* __restrict__ qa, const float* __restrict__ gs,
    const float* __restrict__ sc, const float* __restrict__ w2,
    const float* __restrict__ b2, const float* __restrict__ bp,
    float* __restrict__ out)
{
    __shared__ float qwT[CONC * 65];   // transposed Q*wp tile: [c][il], pad 65 -> bank (c+il)%32
    __shared__ float scs[16 * CONC];   // [bl][c]
    const int t = threadIdx.x;
    const int i0 = blockIdx.x * 64;
    const int b0 = blockIdx.y * 16;

    // Stage Q tile (64 rows x 128 c), transposed, scaled by wp[c]. Coalesced global reads.
#pragma unroll
    for (int k = 0; k < 32; ++k) {
        int idx = k * 256 + t;
        int c = idx & 127, il = idx >> 7;
        qwT[c * 65 + il] = Q[(size_t)(i0 + il) * CONC + c] * wp[c];
    }
    // Stage stu_conc tile (16 rows x 128 c).
#pragma unroll
    for (int k = 0; k < 8; ++k) {
        int idx = k * 256 + t;
        int c = idx & 127, bl = idx >> 7;
        scs[bl * CONC + c] = sc[(b0 + bl) * CONC + c];
    }
    __syncthreads();

    const int il = t & 63;     // i within tile (lane dim -> coalesced store)
    const int bg = t >> 6;     // b group: 4 b's each
    float acc0 = 0.f, acc1 = 0.f, acc2 = 0.f, acc3 = 0.f;
#pragma unroll 4
    for (int c = 0; c < CONC; ++c) {
        float qv = qwT[c * 65 + il];                 // conflict-free
        acc0 += qv * scs[(bg * 4 + 0) * CONC + c];   // wave-uniform broadcast
        acc1 += qv * scs[(bg * 4 + 1) * CONC + c];
        acc2 += qv * scs[(bg * 4 + 2) * CONC + c];
        acc3 += qv * scs[(bg * 4 + 3) * CONC + c];
    }

    const int i = i0 + il;
    float d = disc[i], ti = t_arr[i], qai = qa[i];
    float W2 = w2[0], B2 = b2[0], BP = bp[0];
    float accs[4] = {acc0, acc1, acc2, acc3};
#pragma unroll
    for (int k = 0; k < 4; ++k) {
        int b = b0 + bg * 4 + k;
        float P  = sigmoidf(d * (accs[k] - ti) + BP);
        float g1 = sigmoidf(gs[b] + qai);
        float g2 = sigmoidf(g1 * W2 + B2);
        out[(size_t)b * ITEM + i] = g2 + (1.f - g2) * P;
    }
}

extern "C" void kernel_launch(void* const* d_in, const int* in_sizes, int n_in,
                              void* d_out, int out_size, void* d_ws, size_t ws_size,
                              hipStream_t stream) {
    const int*   stu_list = (const int*)d_in[0];
    const float* stu_emb  = (const float*)d_in[1];
    const float* item_emb = (const float*)d_in[2];
    const float* disc     = (const float*)d_in[3];
    const float* Q        = (const float*)d_in[4];
    const float* w1       = (const float*)d_in[5];
    const float* b1       = (const float*)d_in[6];
    const float* wp       = (const float*)d_in[7];
    const float* bp       = (const float*)d_in[8];
    const float* gw_stu   = (const float*)d_in[9];
    const float* gw_Q     = (const float*)d_in[10];
    const float* w2       = (const float*)d_in[11];
    const float* b2       = (const float*)d_in[12];
    float* out = (float*)d_out;

    float* ws    = (float*)d_ws;
    float* sc    = ws;                 // 16384 floats
    float* gs    = ws + 16384;         // 128
    float* t_arr = ws + 16512;         // 8000
    float* qa    = ws + 24512;         // 8000  (total 32512 floats = 127 KiB)

    stu_kernel<<<64, 256, 0, stream>>>(stu_list, stu_emb, w1, b1, gw_stu, sc, gs);
    item_kernel<<<(ITEM / 4), 256, 0, stream>>>(item_emb, Q, w1, b1, wp, gw_Q, t_arr, qa);
    out_kernel<<<dim3(ITEM / 64, BATCH / 16), 256, 0, stream>>>(Q, wp, disc, t_arr, qa, gs, sc, w2, b2, bp, out);
}

// Round 4
// 103.881 us; speedup vs baseline: 1.1521x; 1.1521x over previous
//
#include <hip/hip_runtime.h>
#include <hip/hip_bf16.h>

#define STU  20000
#define ITEM 8000
#define CONC 128
#define EMB  32
#define BATCH 128

typedef short s16x8 __attribute__((ext_vector_type(8)));   // 8 bf16 (4 VGPRs) MFMA frag
typedef float f32x4 __attribute__((ext_vector_type(4)));   // MFMA accumulator

__device__ __forceinline__ float sigmoidf(float x) { return 1.f / (1.f + __expf(-x)); }

// ---------------- Kernel 1: scb[b][c] = bf16(sigmoid(stu_emb[idx[b]].w1[c]+b1[c]) - 0.5); gs[b] = gw_stu[idx[b]]
__global__ __launch_bounds__(256) void stu_kernel(
    const int* __restrict__ stu_list, const float* __restrict__ stu_emb,
    const float* __restrict__ w1, const float* __restrict__ b1,
    const float* __restrict__ gw_stu,
    __hip_bfloat16* __restrict__ scb_out,  // [BATCH][CONC] bf16, centered
    float* __restrict__ gs_out)            // [BATCH]
{
    int tid = blockIdx.x * 256 + threadIdx.x;   // grid 64 -> 16384 threads
    int b = tid >> 7, c = tid & 127;
    int sid = stu_list[b] - 1;
    float d = b1[c];
    const float4* wrow = (const float4*)(w1 + c * EMB);
    const float4* erow = (const float4*)(stu_emb + (size_t)sid * EMB);
#pragma unroll
    for (int e4 = 0; e4 < EMB / 4; ++e4) {
        float4 w = wrow[e4], em = erow[e4];
        d += w.x * em.x + w.y * em.y + w.z * em.z + w.w * em.w;
    }
    scb_out[tid] = __float2bfloat16(sigmoidf(d) - 0.5f);
    if (c == 0) gs_out[b] = gw_stu[sid];
}

// ---------------- Kernel 2: per item i (8 items per wave, w1 rows held in VGPRs):
//   qwb[i][c] = bf16(Q[i,c]*wp[c])
//   t2[i] = sum_c Q*wp*item_conc - 0.5*sum_c Q*wp      (centered-t)
//   qa[i] = sum_c Q[i,c]*gw_Q[c]
__global__ __launch_bounds__(256) void item_kernel(
    const float* __restrict__ item_emb, const float* __restrict__ Q,
    const float* __restrict__ w1, const float* __restrict__ b1,
    const float* __restrict__ wp, const float* __restrict__ gw_Q,
    __hip_bfloat16* __restrict__ qwb_out,  // [ITEM][CONC] bf16
    float* __restrict__ t2_out,            // [ITEM]
    float* __restrict__ qa_out)            // [ITEM]
{
    const int wave = (blockIdx.x * 256 + threadIdx.x) >> 6;  // 0..999
    const int lane = threadIdx.x & 63;
    const int c0 = lane, c1 = lane + 64;

    float4 wa[8], wb[8];
    const float4* w0p = (const float4*)(w1 + c0 * EMB);
    const float4* w1p = (const float4*)(w1 + c1 * EMB);
#pragma unroll
    for (int j = 0; j < 8; ++j) { wa[j] = w0p[j]; wb[j] = w1p[j]; }
    const float b10 = b1[c0], b11 = b1[c1];
    const float wp0 = wp[c0], wp1 = wp[c1];
    const float gq0 = gw_Q[c0], gq1 = gw_Q[c1];

    for (int n = 0; n < 8; ++n) {
        const int i = wave * 8 + n;
        const float4* ep = (const float4*)(item_emb + (size_t)i * EMB);
        float d0 = b10, d1 = b11;
#pragma unroll
        for (int j = 0; j < 8; ++j) {
            float4 e = ep[j];
            d0 += wa[j].x * e.x + wa[j].y * e.y + wa[j].z * e.z + wa[j].w * e.w;
            d1 += wb[j].x * e.x + wb[j].y * e.y + wb[j].z * e.z + wb[j].w * e.w;
        }
        float ic0 = sigmoidf(d0), ic1 = sigmoidf(d1);
        float q0 = Q[(size_t)i * CONC + c0], q1 = Q[(size_t)i * CONC + c1];
        float u0 = q0 * wp0, u1 = q1 * wp1;
        qwb_out[(size_t)i * CONC + c0] = __float2bfloat16(u0);
        qwb_out[(size_t)i * CONC + c1] = __float2bfloat16(u1);
        float at = u0 * ic0 + u1 * ic1;
        float as = u0 + u1;
        float aq = q0 * gq0 + q1 * gq1;
#pragma unroll
        for (int off = 32; off; off >>= 1) {
            at += __shfl_xor(at, off);
            as += __shfl_xor(as, off);
            aq += __shfl_xor(aq, off);
        }
        if (lane == 0) { t2_out[i] = at - 0.5f * as; qa_out[i] = aq; }
    }
}

// ---------------- Kernel 3: MFMA GEMM + epilogue. One wave = one 16b x 16i tile, K=128 via 4 mfma.
// A = scb [128b x 128c] bf16 row-major; B^T = qwb [8000i x 128c] bf16 row-major (gemm_bt fragment scheme).
__global__ __launch_bounds__(256) void out_mfma(
    const __hip_bfloat16* __restrict__ qwb, const __hip_bfloat16* __restrict__ scb,
    const float* __restrict__ disc, const float* __restrict__ t2,
    const float* __restrict__ qa, const float* __restrict__ gs,
    const float* __restrict__ w2, const float* __restrict__ b2,
    const float* __restrict__ bpp,
    float* __restrict__ out)
{
    const int wid  = (blockIdx.x * 256 + threadIdx.x) >> 6;  // 0..3999
    const int lane = threadIdx.x & 63;
    const int it = wid % 500, bt = wid / 500;                // 500 i-tiles x 8 b-tiles
    const int i0 = it * 16, b0 = bt * 16;
    const int l15 = lane & 15, lk = lane >> 4;

    const s16x8* ap  = (const s16x8*)((const short*)scb + (b0 + l15) * CONC + lk * 8);
    const s16x8* bp8 = (const s16x8*)((const short*)qwb + (size_t)(i0 + l15) * CONC + lk * 8);

    f32x4 acc = {0.f, 0.f, 0.f, 0.f};
#pragma unroll
    for (int ks = 0; ks < 4; ++ks)   // k-step = 32 concepts = 4 s16x8 units
        acc = __builtin_amdgcn_mfma_f32_16x16x32_bf16(ap[ks * 4], bp8[ks * 4], acc, 0, 0, 0);

    const int i = i0 + l15;
    const float di = disc[i], ti = t2[i], qi = qa[i];
    const float W2 = w2[0], B2 = b2[0], BP = bpp[0];
#pragma unroll
    for (int r = 0; r < 4; ++r) {
        const int b = b0 + lk * 4 + r;                       // D row = (lane>>4)*4 + reg
        float P  = sigmoidf(di * (acc[r] - ti) + BP);
        float g1 = sigmoidf(gs[b] + qi);
        float g2 = sigmoidf(fmaf(g1, W2, B2));
        out[(size_t)b * ITEM + i] = g2 + (1.f - g2) * P;
    }
}

extern "C" void kernel_launch(void* const* d_in, const int* in_sizes, int n_in,
                              void* d_out, int out_size, void* d_ws, size_t ws_size,
                              hipStream_t stream) {
    const int*   stu_list = (const int*)d_in[0];
    const float* stu_emb  = (const float*)d_in[1];
    const float* item_emb = (const float*)d_in[2];
    const float* disc     = (const float*)d_in[3];
    const float* Q        = (const float*)d_in[4];
    const float* w1       = (const float*)d_in[5];
    const float* b1       = (const float*)d_in[6];
    const float* wp       = (const float*)d_in[7];
    const float* bp       = (const float*)d_in[8];
    const float* gw_stu   = (const float*)d_in[9];
    const float* gw_Q     = (const float*)d_in[10];
    const float* w2       = (const float*)d_in[11];
    const float* b2       = (const float*)d_in[12];
    float* out = (float*)d_out;

    char* ws = (char*)d_ws;
    __hip_bfloat16* scb = (__hip_bfloat16*)ws;                       // 128*128*2 = 32 KiB
    float* gs  = (float*)(ws + 32768);                               // 128
    float* t2  = gs + BATCH;                                         // 8000
    float* qa  = t2 + ITEM;                                          // 8000
    __hip_bfloat16* qwb = (__hip_bfloat16*)(ws + 32768 + 4 * (BATCH + 2 * ITEM)); // 2 MiB, 16B-aligned

    stu_kernel<<<64, 256, 0, stream>>>(stu_list, stu_emb, w1, b1, gw_stu, scb, gs);
    item_kernel<<<250, 256, 0, stream>>>(item_emb, Q, w1, b1, wp, gw_Q, qwb, t2, qa);
    out_mfma<<<1000, 256, 0, stream>>>(qwb, scb, disc, t2, qa, gs, w2, b2, bp, out);
}

// Round 7
// 92.204 us; speedup vs baseline: 1.2980x; 1.1266x over previous
//
#include <hip/hip_runtime.h>
#include <hip/hip_bf16.h>

#define ITEM 8000
#define CONC 128
#define EMB  32
#define BATCH 128
#define NBLK 500          // ITEM / IB
#define IB   16           // items per block
#define SE_S 56           // row stride (shorts) for [*][32] bf16 LDS tiles (112 B = 7*16, banks +28)
#define SC_S 136          // row stride (shorts) for [*][128] bf16 LDS tiles (272 B = 17*16, banks +4)

typedef short s16x8 __attribute__((ext_vector_type(8)));   // 8 bf16 = one MFMA input frag
typedef float f32x4 __attribute__((ext_vector_type(4)));   // MFMA accumulator

__device__ __forceinline__ float sigmoidf(float x) { return 1.f / (1.f + __expf(-x)); }
__device__ __forceinline__ short f2bf(float x) {
    __hip_bfloat16 h = __float2bfloat16(x);
    return *reinterpret_cast<short*>(&h);
}
// convert 16 consecutive floats -> 16 bf16 shorts, two 16B LDS writes
__device__ __forceinline__ void cvt16(const float4* __restrict__ src, short* dst) {
    float4 f0 = src[0], f1 = src[1], f2 = src[2], f3 = src[3];
    s16x8 a, b;
    a[0]=f2bf(f0.x); a[1]=f2bf(f0.y); a[2]=f2bf(f0.z); a[3]=f2bf(f0.w);
    a[4]=f2bf(f1.x); a[5]=f2bf(f1.y); a[6]=f2bf(f1.z); a[7]=f2bf(f1.w);
    b[0]=f2bf(f2.x); b[1]=f2bf(f2.y); b[2]=f2bf(f2.z); b[3]=f2bf(f2.w);
    b[4]=f2bf(f3.x); b[5]=f2bf(f3.y); b[6]=f2bf(f3.z); b[7]=f2bf(f3.w);
    *(s16x8*)dst = a;
    *(s16x8*)(dst + 8) = b;
}

// One kernel, zero global scratch. Block = 256 thr (4 waves), 16 items.
// Phase A: scb[128 b][128 c] = bf16(sigmoid(stu_emb[idx] . w1^T + b1) - 0.5)   (MFMA, K=32)
// Phase B: qw[16 i][128 c] = bf16(Q*wp); t2[i] = sum_c qw*(ic-0.5); qa[i] = sum_c Q*gw_Q
// Phase C: A2[b,i] = sum_c scb*qw (MFMA, K=128); out = g2 + (1-g2)*sigmoid(disc*(A2-t2)+bp)
__global__ __launch_bounds__(256) void fused_kernel(
    const int* __restrict__ stu_list, const float* __restrict__ stu_emb,
    const float* __restrict__ item_emb, const float* __restrict__ disc,
    const float* __restrict__ Q, const float* __restrict__ w1,
    const float* __restrict__ b1, const float* __restrict__ wp,
    const float* __restrict__ bp_, const float* __restrict__ gw_stu,
    const float* __restrict__ gw_Q, const float* __restrict__ w2,
    const float* __restrict__ b2, float* __restrict__ out)
{
    __shared__ __align__(16) short sembL[BATCH * SE_S];   // 14336 B
    __shared__ __align__(16) short w1L  [CONC * SE_S];    // 14336 B
    __shared__ __align__(16) short itembL[IB * SE_S];     // 1792 B
    __shared__ __align__(16) short scbL [BATCH * SC_S];   // 34816 B
    __shared__ __align__(16) short qwL  [IB * SC_S];      // 4352 B
    __shared__ float ptT[4][IB], ptQ[4][IB], gsL[BATCH];  // 1024 B   (total ~70.7 KB -> 2 blk/CU)

    const int tid = threadIdx.x;
    const int i0  = blockIdx.x * IB;
    const int w   = tid >> 6;           // wave 0..3
    const int lane = tid & 63;
    const int l15 = lane & 15, lk = lane >> 4;

    // ---------------- staging: fp32 -> bf16 LDS ----------------
    {
        int row = tid >> 1, half = tid & 1;               // 2 threads per row, 16 floats each
        int sid = stu_list[row] - 1;
        cvt16((const float4*)(stu_emb + (size_t)sid * EMB + half * 16),
              &sembL[row * SE_S + half * 16]);
        cvt16((const float4*)(w1 + row * EMB + half * 16),
              &w1L[row * SE_S + half * 16]);
        if (tid < 2 * IB) {
            int ir = tid >> 1, ih = tid & 1;
            cvt16((const float4*)(item_emb + (size_t)(i0 + ir) * EMB + ih * 16),
                  &itembL[ir * SE_S + ih * 16]);
        }
        if (tid < BATCH) gsL[tid] = gw_stu[stu_list[tid] - 1];
    }
    __syncthreads();

    // ---------------- phase A: scb via MFMA (wave w -> b-tiles 2w, 2w+1) ----------------
    {
        s16x8 af0 = *(const s16x8*)&sembL[((2 * w + 0) * 16 + l15) * SE_S + lk * 8];
        s16x8 af1 = *(const s16x8*)&sembL[((2 * w + 1) * 16 + l15) * SE_S + lk * 8];
#pragma unroll
        for (int ct = 0; ct < 8; ++ct) {
            s16x8 bf = *(const s16x8*)&w1L[(ct * 16 + l15) * SE_S + lk * 8];
            int c = ct * 16 + l15;
            float bc = b1[c];
            f32x4 z = {0.f, 0.f, 0.f, 0.f};
            f32x4 d0 = __builtin_amdgcn_mfma_f32_16x16x32_bf16(af0, bf, z, 0, 0, 0);
            f32x4 d1 = __builtin_amdgcn_mfma_f32_16x16x32_bf16(af1, bf, z, 0, 0, 0);
#pragma unroll
            for (int r = 0; r < 4; ++r) {   // D: row=(lk*4+r) in b, col=l15 in c (m89 mapping)
                scbL[((2 * w + 0) * 16 + lk * 4 + r) * SC_S + c] = f2bf(sigmoidf(d0[r] + bc) - 0.5f);
                scbL[((2 * w + 1) * 16 + lk * 4 + r) * SC_S + c] = f2bf(sigmoidf(d1[r] + bc) - 0.5f);
            }
        }
    }

    // ---------------- phase B: items (wave w -> c-tiles 2w, 2w+1) ----------------
    {
        s16x8 iaf = *(const s16x8*)&itembL[l15 * SE_S + lk * 8];
        float at[4] = {0.f, 0.f, 0.f, 0.f}, aq[4] = {0.f, 0.f, 0.f, 0.f};
#pragma unroll
        for (int j = 0; j < 2; ++j) {
            int ct = 2 * w + j;
            int c  = ct * 16 + l15;
            s16x8 bf = *(const s16x8*)&w1L[(ct * 16 + l15) * SE_S + lk * 8];
            f32x4 z = {0.f, 0.f, 0.f, 0.f};
            f32x4 d = __builtin_amdgcn_mfma_f32_16x16x32_bf16(iaf, bf, z, 0, 0, 0);
            float bc = b1[c], wpc = wp[c], gqc = gw_Q[c];
#pragma unroll
            for (int r = 0; r < 4; ++r) {   // D row = item (lk*4+r), col = c
                int it = lk * 4 + r;
                float ic = sigmoidf(d[r] + bc);
                float q  = Q[(size_t)(i0 + it) * CONC + c];
                float u  = q * wpc;
                qwL[it * SC_S + c] = f2bf(u);
                at[r] += u * (ic - 0.5f);   // centered-t accumulation
                aq[r] += q * gqc;
            }
        }
#pragma unroll
        for (int off = 1; off < 16; off <<= 1) {
#pragma unroll
            for (int r = 0; r < 4; ++r) {
                at[r] += __shfl_xor(at[r], off);
                aq[r] += __shfl_xor(aq[r], off);
            }
        }
        if (l15 == 0) {
#pragma unroll
            for (int r = 0; r < 4; ++r) { ptT[w][lk * 4 + r] = at[r]; ptQ[w][lk * 4 + r] = aq[r]; }
        }
    }
    __syncthreads();

    // ---------------- phase C: out GEMM (wave w -> b-tiles 2w, 2w+1; one i-tile) ----------------
    {
        s16x8 bfr[4];
#pragma unroll
        for (int ks = 0; ks < 4; ++ks)
            bfr[ks] = *(const s16x8*)&qwL[l15 * SC_S + ks * 32 + lk * 8];

        const int i = i0 + l15;
        const float di = disc[i];
        const float ti = ptT[0][l15] + ptT[1][l15] + ptT[2][l15] + ptT[3][l15];
        const float qi = ptQ[0][l15] + ptQ[1][l15] + ptQ[2][l15] + ptQ[3][l15];
        const float W2 = w2[0], B2 = b2[0], BP = bp_[0];
#pragma unroll
        for (int j = 0; j < 2; ++j) {
            const int bt = 2 * w + j;
            f32x4 acc = {0.f, 0.f, 0.f, 0.f};
#pragma unroll
            for (int ks = 0; ks < 4; ++ks) {
                s16x8 af = *(const s16x8*)&scbL[(bt * 16 + l15) * SC_S + ks * 32 + lk * 8];
                acc = __builtin_amdgcn_mfma_f32_16x16x32_bf16(af, bfr[ks], acc, 0, 0, 0);
            }
#pragma unroll
            for (int r = 0; r < 4; ++r) {
                int b = bt * 16 + lk * 4 + r;
                float P  = sigmoidf(di * (acc[r] - ti) + BP);
                float g1 = sigmoidf(gsL[b] + qi);
                float g2 = sigmoidf(fmaf(g1, W2, B2));
                out[(size_t)b * ITEM + i] = g2 + (1.f - g2) * P;
            }
        }
    }
}

extern "C" void kernel_launch(void* const* d_in, const int* in_sizes, int n_in,
                              void* d_out, int out_size, void* d_ws, size_t ws_size,
                              hipStream_t stream) {
    const int*   stu_list = (const int*)d_in[0];
    const float* stu_emb  = (const float*)d_in[1];
    const float* item_emb = (const float*)d_in[2];
    const float* disc     = (const float*)d_in[3];
    const float* Q        = (const float*)d_in[4];
    const float* w1       = (const float*)d_in[5];
    const float* b1       = (const float*)d_in[6];
    const float* wp       = (const float*)d_in[7];
    const float* bp       = (const float*)d_in[8];
    const float* gw_stu   = (const float*)d_in[9];
    const float* gw_Q     = (const float*)d_in[10];
    const float* w2       = (const float*)d_in[11];
    const float* b2       = (const float*)d_in[12];
    float* out = (float*)d_out;

    fused_kernel<<<NBLK, 256, 0, stream>>>(stu_list, stu_emb, item_emb, disc, Q,
                                           w1, b1, wp, bp, gw_stu, gw_Q, w2, b2, out);
}

// Round 9
// 90.887 us; speedup vs baseline: 1.3168x; 1.0145x over previous
//
#include <hip/hip_runtime.h>
#include <hip/hip_bf16.h>

#define ITEM 8000
#define CONC 128
#define EMB  32
#define BATCH 128
#define IB   32           // items per block
#define NBLK 250          // ITEM / IB
#define SE_S 56           // row stride (shorts) for [*][32] bf16 LDS tiles (112 B)
#define SC_S 136          // row stride (shorts) for [*][128] bf16 LDS tiles (272 B)

typedef short s16x8 __attribute__((ext_vector_type(8)));   // 8 bf16 = one MFMA input frag
typedef float f32x4 __attribute__((ext_vector_type(4)));   // MFMA accumulator

__device__ __forceinline__ float sigmoidf(float x) { return 1.f / (1.f + __expf(-x)); }
__device__ __forceinline__ short f2bf(float x) {
    __hip_bfloat16 h = __float2bfloat16(x);
    return *reinterpret_cast<short*>(&h);
}
// convert 16 consecutive floats -> 16 bf16 shorts, two 16B LDS writes
__device__ __forceinline__ void cvt16(const float4* __restrict__ src, short* dst) {
    float4 f0 = src[0], f1 = src[1], f2 = src[2], f3 = src[3];
    s16x8 a, b;
    a[0]=f2bf(f0.x); a[1]=f2bf(f0.y); a[2]=f2bf(f0.z); a[3]=f2bf(f0.w);
    a[4]=f2bf(f1.x); a[5]=f2bf(f1.y); a[6]=f2bf(f1.z); a[7]=f2bf(f1.w);
    b[0]=f2bf(f2.x); b[1]=f2bf(f2.y); b[2]=f2bf(f2.z); b[3]=f2bf(f2.w);
    b[4]=f2bf(f3.x); b[5]=f2bf(f3.y); b[6]=f2bf(f3.z); b[7]=f2bf(f3.w);
    *(s16x8*)dst = a;
    *(s16x8*)(dst + 8) = b;
}

// One kernel, zero global scratch. Block = 512 thr (8 waves), 32 items.
// Phase A: scb[128 b][128 c] = bf16(sigmoid(stu_emb[idx].w1^T + b1) - 0.5)  (wave w -> b-tile w)
// Phase B: qw[32 i][128 c] = bf16(Q*wp); t2/qa partials              (wave w -> c-tile w, 2 i-tiles)
// Phase C: A2 = scb x qw^T via MFMA K=128 + epilogue                 (wave w -> b-tile w, 2 i-tiles)
__global__ __launch_bounds__(512) void fused_kernel(
    const int* __restrict__ stu_list, const float* __restrict__ stu_emb,
    const float* __restrict__ item_emb, const float* __restrict__ disc,
    const float* __restrict__ Q, const float* __restrict__ w1,
    const float* __restrict__ b1, const float* __restrict__ wp,
    const float* __restrict__ bp_, const float* __restrict__ gw_stu,
    const float* __restrict__ gw_Q, const float* __restrict__ w2,
    const float* __restrict__ b2, float* __restrict__ out)
{
    __shared__ __align__(16) short sembL[BATCH * SE_S];   // 14336 B
    __shared__ __align__(16) short w1L  [CONC * SE_S];    // 14336 B
    __shared__ __align__(16) short itembL[IB * SE_S];     // 3584 B
    __shared__ __align__(16) short scbL [BATCH * SC_S];   // 34816 B
    __shared__ __align__(16) short qwL  [IB * SC_S];      // 8704 B
    __shared__ float ptT[8][IB], ptQ[8][IB], gsL[BATCH];  // 2560 B   (total ~76.5 KB)

    const int tid = threadIdx.x;
    const int i0  = blockIdx.x * IB;
    const int w   = tid >> 6;           // wave 0..7
    const int lane = tid & 63;
    const int l15 = lane & 15, lk = lane >> 4;

    // ---------------- staging: fp32 -> bf16 LDS ----------------
    {
        int r2 = (tid & 255) >> 1, half = tid & 1;        // one cvt16 per thread
        if (tid < 256) {
            int sid = stu_list[r2] - 1;
            cvt16((const float4*)(stu_emb + (size_t)sid * EMB + half * 16),
                  &sembL[r2 * SE_S + half * 16]);
        } else {
            cvt16((const float4*)(w1 + r2 * EMB + half * 16),
                  &w1L[r2 * SE_S + half * 16]);
        }
        if (tid < 2 * IB) {
            int ir = tid >> 1, ih = tid & 1;
            cvt16((const float4*)(item_emb + (size_t)(i0 + ir) * EMB + ih * 16),
                  &itembL[ir * SE_S + ih * 16]);
        }
        if (tid < BATCH) gsL[tid] = gw_stu[stu_list[tid] - 1];
    }
    __syncthreads();

    // ---------------- phase A: scb via MFMA (wave w -> b-tile w) ----------------
    {
        s16x8 af = *(const s16x8*)&sembL[(w * 16 + l15) * SE_S + lk * 8];
#pragma unroll
        for (int ct = 0; ct < 8; ++ct) {
            s16x8 bf = *(const s16x8*)&w1L[(ct * 16 + l15) * SE_S + lk * 8];
            int c = ct * 16 + l15;
            float bc = b1[c];
            f32x4 z = {0.f, 0.f, 0.f, 0.f};
            f32x4 d = __builtin_amdgcn_mfma_f32_16x16x32_bf16(af, bf, z, 0, 0, 0);
#pragma unroll
            for (int r = 0; r < 4; ++r)    // D: row=(lk*4+r) in b, col=l15 in c (m89 mapping)
                scbL[(w * 16 + lk * 4 + r) * SC_S + c] = f2bf(sigmoidf(d[r] + bc) - 0.5f);
        }
    }

    // ---------------- phase B: items (wave w -> c-tile w, both i-tiles) ----------------
    {
        s16x8 ia0 = *(const s16x8*)&itembL[l15 * SE_S + lk * 8];
        s16x8 ia1 = *(const s16x8*)&itembL[(16 + l15) * SE_S + lk * 8];
        s16x8 bf  = *(const s16x8*)&w1L[(w * 16 + l15) * SE_S + lk * 8];
        const int c = w * 16 + l15;
        const float bc = b1[c], wpc = wp[c], gqc = gw_Q[c];
        f32x4 z = {0.f, 0.f, 0.f, 0.f};
        f32x4 d0 = __builtin_amdgcn_mfma_f32_16x16x32_bf16(ia0, bf, z, 0, 0, 0);
        f32x4 d1 = __builtin_amdgcn_mfma_f32_16x16x32_bf16(ia1, bf, z, 0, 0, 0);
        float at[8], aq[8];
#pragma unroll
        for (int j = 0; j < 2; ++j) {
#pragma unroll
            for (int r = 0; r < 4; ++r) {  // D row = item-within-tile (lk*4+r), col = c
                int it = j * 16 + lk * 4 + r;
                float dv = (j ? d1[r] : d0[r]);
                float ic = sigmoidf(dv + bc);
                float q  = Q[(size_t)(i0 + it) * CONC + c];
                float u  = q * wpc;
                qwL[it * SC_S + c] = f2bf(u);
                at[j * 4 + r] = u * (ic - 0.5f);   // centered-t
                aq[j * 4 + r] = q * gqc;
            }
        }
#pragma unroll
        for (int off = 1; off < 16; off <<= 1) {
#pragma unroll
            for (int k = 0; k < 8; ++k) {
                at[k] += __shfl_xor(at[k], off);
                aq[k] += __shfl_xor(aq[k], off);
            }
        }
        if (l15 == 0) {
#pragma unroll
            for (int k = 0; k < 8; ++k) {
                int it = (k >> 2) * 16 + lk * 4 + (k & 3);
                ptT[w][it] = at[k];
                ptQ[w][it] = aq[k];
            }
        }
    }
    __syncthreads();

    // ---------------- phase C: out GEMM (wave w -> b-tile w, i-tiles j=0,1) ----------------
    {
        s16x8 af[4];
#pragma unroll
        for (int ks = 0; ks < 4; ++ks)
            af[ks] = *(const s16x8*)&scbL[(w * 16 + l15) * SC_S + ks * 32 + lk * 8];

        const float W2 = w2[0], B2 = b2[0], BP = bp_[0];
#pragma unroll
        for (int j = 0; j < 2; ++j) {
            f32x4 acc = {0.f, 0.f, 0.f, 0.f};
#pragma unroll
            for (int ks = 0; ks < 4; ++ks) {
                s16x8 bfr = *(const s16x8*)&qwL[(j * 16 + l15) * SC_S + ks * 32 + lk * 8];
                acc = __builtin_amdgcn_mfma_f32_16x16x32_bf16(af[ks], bfr, acc, 0, 0, 0);
            }
            const int il = j * 16 + l15;
            const int i  = i0 + il;
            const float di = disc[i];
            float ti = 0.f, qi = 0.f;
#pragma unroll
            for (int w8 = 0; w8 < 8; ++w8) { ti += ptT[w8][il]; qi += ptQ[w8][il]; }
#pragma unroll
            for (int r = 0; r < 4; ++r) {  // D row = b-within-tile (lk*4+r), col = i-within-tile
                int b = w * 16 + lk * 4 + r;
                float P  = sigmoidf(di * (acc[r] - ti) + BP);
                float g1 = sigmoidf(gsL[b] + qi);
                float g2 = sigmoidf(fmaf(g1, W2, B2));
                out[(size_t)b * ITEM + i] = g2 + (1.f - g2) * P;
            }
        }
    }
}

extern "C" void kernel_launch(void* const* d_in, const int* in_sizes, int n_in,
                              void* d_out, int out_size, void* d_ws, size_t ws_size,
                              hipStream_t stream) {
    const int*   stu_list = (const int*)d_in[0];
    const float* stu_emb  = (const float*)d_in[1];
    const float* item_emb = (const float*)d_in[2];
    const float* disc     = (const float*)d_in[3];
    const float* Q        = (const float*)d_in[4];
    const float* w1       = (const float*)d_in[5];
    const float* b1       = (const float*)d_in[6];
    const float* wp       = (const float*)d_in[7];
    const float* bp       = (const float*)d_in[8];
    const float* gw_stu   = (const float*)d_in[9];
    const float* gw_Q     = (const float*)d_in[10];
    const float* w2       = (const float*)d_in[11];
    const float* b2       = (const float*)d_in[12];
    float* out = (float*)d_out;

    fused_kernel<<<NBLK, 512, 0, stream>>>(stu_list, stu_emb, item_emb, disc, Q,
                                           w1, b1, wp, bp, gw_stu, gw_Q, w2, b2, out);
}